// Round 2
// baseline (181.644 us; speedup 1.0000x reference)
//
#include <hip/hip_runtime.h>

// RankingLoss via bucket-ordering, 3 wide kernels, no single-block dispatches,
// no global zero-init, no global atomics in the sort:
//   K1 hist_k   (32 blocks): private per-block histograms H[bin][blk] (LDS-built).
//   K2 scatter_k(32 blocks): each block redundantly scans H (cheap, parallel) ->
//                            exact position = B[bin] + prev-blocks-count + LDS rank.
//   K3 rank_k (1024 blocks): sorted-prefix hinge sums; full region = 3 VALU/pair,
//                            band = compare+ballot; fused final mean via
//                            last-block-done pattern (deterministic double sum).

constexpr float MARGIN = 0.1f;
constexpr int NBINS = 4096;
constexpr int HB    = 32;     // histogram blocks == scatter blocks (ranges must match)
constexpr int RT    = 16;     // rows per rank block
constexpr int T     = 256;    // threads per block

__device__ __forceinline__ int bin_of(float t) {
    int b = (int)(t * (float)NBINS);   // monotone; equal t -> equal bin
    b = b < 0 ? 0 : (b > NBINS - 1 ? NBINS - 1 : b);
    return b;
}

// K1: per-block private histograms, H[bin*HB + blk]. No global zeroing needed.
__global__ __launch_bounds__(T) void hist_k(const float* __restrict__ target,
                                            int* __restrict__ H, int n) {
    __shared__ int lh[NBINS];
    for (int i = (int)threadIdx.x; i < NBINS; i += T) lh[i] = 0;
    __syncthreads();
    const int per  = n / HB;
    const int base = (int)blockIdx.x * per;
    for (int i = (int)threadIdx.x; i < per; i += T)
        atomicAdd(&lh[bin_of(target[base + i])], 1);
    __syncthreads();
    for (int i = (int)threadIdx.x; i < NBINS; i += T)
        H[i * HB + (int)blockIdx.x] = lh[i];
}

// K2: redundant in-block scan of H + exact scatter (no global atomics).
__global__ __launch_bounds__(T) void scatter_k(const float* __restrict__ pred,
                                               const float* __restrict__ target,
                                               const int* __restrict__ H,
                                               float* __restrict__ ts,
                                               float* __restrict__ ps,
                                               int* __restrict__ Bg,
                                               int* __restrict__ done, int n) {
    __shared__ int bbase[NBINS];   // exclusive bin prefix (global start of bin)
    __shared__ int prevk[NBINS];   // count of this bin in element-blocks < k
    __shared__ int lcnt[NBINS];    // local (within-block) rank counters
    __shared__ int wsum[T / 64];

    const int tid = (int)threadIdx.x;
    const int k   = (int)blockIdx.x;
    constexpr int BPT = NBINS / T;          // 16 bins per thread
    const int b0 = tid * BPT;

    int tot[BPT], prv[BPT];
    int s = 0;
    #pragma unroll
    for (int u = 0; u < BPT; ++u) {
        const int b = b0 + u;
        const int4* h4 = (const int4*)(H + b * HB);
        int t = 0, pv = 0;
        #pragma unroll
        for (int q = 0; q < HB / 4; ++q) {
            int4 v = h4[q];
            t += v.x + v.y + v.z + v.w;
            const int blk = q * 4;
            pv += (blk + 0 < k ? v.x : 0) + (blk + 1 < k ? v.y : 0)
                + (blk + 2 < k ? v.z : 0) + (blk + 3 < k ? v.w : 0);
        }
        tot[u] = t; prv[u] = pv; s += t;
        lcnt[b] = 0;
    }

    // exclusive prefix of per-thread sums across the block
    int incl = s;
    #pragma unroll
    for (int off = 1; off < 64; off <<= 1) {
        int v = __shfl_up(incl, off, 64);
        if ((tid & 63) >= off) incl += v;
    }
    if ((tid & 63) == 63) wsum[tid >> 6] = incl;
    __syncthreads();
    int woff = 0;
    for (int w = 0; w < (tid >> 6); ++w) woff += wsum[w];
    int run = woff + incl - s;
    #pragma unroll
    for (int u = 0; u < BPT; ++u) {
        bbase[b0 + u] = run;
        prevk[b0 + u] = prv[u];
        run += tot[u];
    }
    __syncthreads();

    // scatter this block's element range (same ranges as hist_k!)
    const int per  = n / HB;
    const int base = k * per;
    for (int i = tid; i < per; i += T) {
        const float t = target[base + i];
        const float p = pred[base + i];
        const int b = bin_of(t);
        const int r = atomicAdd(&lcnt[b], 1);      // LDS atomic only
        const int pos = bbase[b] + prevk[b] + r;
        ts[pos] = t;
        ps[pos] = p;
    }

    if (k == 0) {
        for (int b = tid; b < NBINS; b += T) Bg[b] = bbase[b];
        if (tid == 0) { Bg[NBINS] = n; done[0] = 0; }
    }
}

// K3: sorted-prefix hinge sums + fused deterministic final reduction.
__global__ __launch_bounds__(T) void rank_k(const float* __restrict__ ts,
                                            const float* __restrict__ ps,
                                            const int* __restrict__ B,
                                            float* __restrict__ partials,
                                            int* __restrict__ done,
                                            float* __restrict__ out, int n) {
    const int nblk = (int)gridDim.x;
    const int g = nblk - 1 - (int)blockIdx.x;   // heavy-first
    const int q = g * RT;

    float ti[RT], ci[RT];
    #pragma unroll
    for (int r = 0; r < RT; ++r) {
        ti[r] = ts[q + r];                       // uniform -> scalar loads
        ci[r] = MARGIN - ps[q + r];
    }

    const int Blo = B[bin_of(ti[0])];            // j < Blo: qualifies for all rows
    const int Bhi = B[bin_of(ti[RT - 1]) + 1];   // j >= Bhi: qualifies for none
    const int M0 = Blo & ~3;
    int M1 = (Bhi + 3) & ~3;
    if (M1 > n) M1 = n;

    float sum[RT];
    #pragma unroll
    for (int r = 0; r < RT; ++r) sum[r] = 0.f;

    const float4* __restrict__ p4 = (const float4*)ps;
    const float4* __restrict__ t4 = (const float4*)ts;

    // Full region: unconditional hinge, 3 VALU/pair.
    const int f4 = M0 >> 2;
    for (int j = (int)threadIdx.x; j < f4; j += T) {
        const float4 pj = p4[j];
        #pragma unroll
        for (int r = 0; r < RT; ++r) {
            sum[r] += fmaxf(0.f, ci[r] + pj.x);
            sum[r] += fmaxf(0.f, ci[r] + pj.y);
            sum[r] += fmaxf(0.f, ci[r] + pj.z);
            sum[r] += fmaxf(0.f, ci[r] + pj.w);
        }
    }

    // Boundary band: exact strict compares + ballot counts.
    unsigned int cnt[RT];
    #pragma unroll
    for (int r = 0; r < RT; ++r) cnt[r] = 0u;

    const int m4lo = M0 >> 2, m4hi = M1 >> 2;
    const int iters = (m4hi - m4lo + T - 1) / T;   // block-uniform
    for (int it = 0; it < iters; ++it) {
        const int j = m4lo + it * T + (int)threadIdx.x;
        const bool inb = j < m4hi;
        const int jc = inb ? j : m4lo;
        const float4 tj = t4[jc];
        const float4 pj = p4[jc];
        #pragma unroll
        for (int r = 0; r < RT; ++r) {
            { bool m = inb && (tj.x < ti[r]); float h = fmaxf(0.f, ci[r] + pj.x);
              sum[r] += m ? h : 0.f; cnt[r] += (unsigned)__popcll(__ballot(m)); }
            { bool m = inb && (tj.y < ti[r]); float h = fmaxf(0.f, ci[r] + pj.y);
              sum[r] += m ? h : 0.f; cnt[r] += (unsigned)__popcll(__ballot(m)); }
            { bool m = inb && (tj.z < ti[r]); float h = fmaxf(0.f, ci[r] + pj.z);
              sum[r] += m ? h : 0.f; cnt[r] += (unsigned)__popcll(__ballot(m)); }
            { bool m = inb && (tj.w < ti[r]); float h = fmaxf(0.f, ci[r] + pj.w);
              sum[r] += m ? h : 0.f; cnt[r] += (unsigned)__popcll(__ballot(m)); }
        }
    }

    // Block-level reduction.
    __shared__ float ls[T / 64][RT];
    __shared__ unsigned int lc[T / 64][RT];
    const int lane = (int)threadIdx.x & 63;
    const int wv   = (int)threadIdx.x >> 6;
    #pragma unroll
    for (int r = 0; r < RT; ++r) {
        float sv = sum[r];
        #pragma unroll
        for (int off = 32; off > 0; off >>= 1) sv += __shfl_down(sv, off, 64);
        if (lane == 0) { ls[wv][r] = sv; lc[wv][r] = cnt[r]; }
    }
    __syncthreads();

    float val = 0.f;
    if ((int)threadIdx.x < RT) {
        float sv = 0.f;
        unsigned int c = (unsigned int)M0;       // full region counts for every row
        #pragma unroll
        for (int w = 0; w < T / 64; ++w) { sv += ls[w][threadIdx.x]; c += lc[w][threadIdx.x]; }
        val = (c > 0u) ? sv / (float)c : 0.f;
    }
    if ((int)threadIdx.x < 64) {                 // lanes 0..15 hold the row values
        #pragma unroll
        for (int off = 8; off > 0; off >>= 1) val += __shfl_down(val, off, 64);
    }
    if (threadIdx.x == 0) partials[blockIdx.x] = val;

    // Last-block-done final reduction (deterministic: fixed order, double acc).
    __threadfence();
    __shared__ int lastflag;
    if (threadIdx.x == 0) {
        const int old = atomicAdd(done, 1);
        lastflag = (old == nblk - 1) ? 1 : 0;
    }
    __syncthreads();
    if (lastflag) {
        __threadfence();
        const volatile float* vp = partials;
        double sd_acc = 0.0;
        for (int i = (int)threadIdx.x; i < nblk; i += T) sd_acc += (double)vp[i];
        #pragma unroll
        for (int off = 32; off > 0; off >>= 1) sd_acc += __shfl_down(sd_acc, off, 64);
        __shared__ double sd[T / 64];
        if (lane == 0) sd[wv] = sd_acc;
        __syncthreads();
        if (threadIdx.x == 0) {
            double tt = 0.0;
            #pragma unroll
            for (int w = 0; w < T / 64; ++w) tt += sd[w];
            out[0] = (float)(tt / (double)n);
        }
    }
}

extern "C" void kernel_launch(void* const* d_in, const int* in_sizes, int n_in,
                              void* d_out, int out_size, void* d_ws, size_t ws_size,
                              hipStream_t stream) {
    const float* pred   = (const float*)d_in[0];
    const float* target = (const float*)d_in[1];
    const int n = in_sizes[0];                 // 16384
    const int nblk = n / RT;                   // 1024

    char* w = (char*)d_ws;
    size_t o = 0;
    auto alloc = [&](size_t bytes) {
        void* p = w + o;
        o = (o + bytes + 255) & ~(size_t)255;
        return p;
    };
    float* ts       = (float*)alloc((size_t)n * 4);
    float* ps       = (float*)alloc((size_t)n * 4);
    int*   H        = (int*)alloc((size_t)NBINS * HB * 4);
    int*   B        = (int*)alloc((size_t)(NBINS + 1) * 4);
    float* partials = (float*)alloc((size_t)nblk * 4);
    int*   done     = (int*)alloc(16);

    hist_k<<<HB, T, 0, stream>>>(target, H, n);
    scatter_k<<<HB, T, 0, stream>>>(pred, target, H, ts, ps, B, done, n);
    rank_k<<<nblk, T, 0, stream>>>(ts, ps, B, partials, done, (float*)d_out, n);
}

// Round 3
// 91.293 us; speedup vs baseline: 1.9897x; 1.9897x over previous
//
#include <hip/hip_runtime.h>

// RankingLoss via bucket-ordering. 4 stream-ordered dispatches, NO device fences
// (round 2's fused last-block-done pattern cost ~60us in __threadfence L2 writebacks).
//   K1 hist_k   (16 blocks): private per-block histograms H[bin][blk] (LDS-built).
//   K2 scatter_k(16 blocks): redundant in-LDS scan of H -> exact sorted position
//                            = binbase + prev-blocks-count + LDS local rank.
//   K3 rank_k (1024 blocks): sorted-prefix hinge sums. Full region: 3 VALU/pair,
//                            no compares. Boundary band: exact compare + ballot.
//   K4 final_k  (1 block):   deterministic fixed-order double sum of partials.

constexpr float MARGIN = 0.1f;
constexpr int NBINS = 2048;
constexpr int HB    = 16;     // histogram blocks == scatter blocks (ranges match)
constexpr int RT    = 16;     // rows per rank block
constexpr int T     = 256;    // threads per block

__device__ __forceinline__ int bin_of(float t) {
    int b = (int)(t * (float)NBINS);   // monotone; equal t -> equal bin
    b = b < 0 ? 0 : (b > NBINS - 1 ? NBINS - 1 : b);
    return b;
}

// K1: per-block private histograms, H[bin*HB + blk]. No global zeroing needed.
__global__ __launch_bounds__(T) void hist_k(const float* __restrict__ target,
                                            int* __restrict__ H, int n) {
    __shared__ int lh[NBINS];
    for (int i = (int)threadIdx.x; i < NBINS; i += T) lh[i] = 0;
    __syncthreads();
    const int per  = n / HB;
    const int base = (int)blockIdx.x * per;
    for (int i = (int)threadIdx.x; i < per; i += T)
        atomicAdd(&lh[bin_of(target[base + i])], 1);
    __syncthreads();
    for (int i = (int)threadIdx.x; i < NBINS; i += T)
        H[i * HB + (int)blockIdx.x] = lh[i];
}

// K2: redundant in-block scan of H + exact scatter (LDS atomics only).
__global__ __launch_bounds__(T) void scatter_k(const float* __restrict__ pred,
                                               const float* __restrict__ target,
                                               const int* __restrict__ H,
                                               float* __restrict__ ts,
                                               float* __restrict__ ps,
                                               int* __restrict__ Bg, int n) {
    __shared__ int bbase[NBINS];   // exclusive bin prefix (global start of bin)
    __shared__ int prevk[NBINS];   // count of this bin in element-blocks < k
    __shared__ int lcnt[NBINS];    // local (within-block) rank counters
    __shared__ int wsum[T / 64];

    const int tid = (int)threadIdx.x;
    const int k   = (int)blockIdx.x;
    constexpr int BPT = NBINS / T;          // 8 bins per thread
    const int b0 = tid * BPT;

    int tot[BPT], prv[BPT];
    int s = 0;
    #pragma unroll
    for (int u = 0; u < BPT; ++u) {
        const int b = b0 + u;
        const int4* h4 = (const int4*)(H + b * HB);
        int t = 0, pv = 0;
        #pragma unroll
        for (int q = 0; q < HB / 4; ++q) {
            int4 v = h4[q];
            t += v.x + v.y + v.z + v.w;
            const int blk = q * 4;
            pv += (blk + 0 < k ? v.x : 0) + (blk + 1 < k ? v.y : 0)
                + (blk + 2 < k ? v.z : 0) + (blk + 3 < k ? v.w : 0);
        }
        tot[u] = t; prv[u] = pv; s += t;
        lcnt[b] = 0;
    }

    // exclusive prefix of per-thread sums across the block
    int incl = s;
    #pragma unroll
    for (int off = 1; off < 64; off <<= 1) {
        int v = __shfl_up(incl, off, 64);
        if ((tid & 63) >= off) incl += v;
    }
    if ((tid & 63) == 63) wsum[tid >> 6] = incl;
    __syncthreads();
    int woff = 0;
    for (int w = 0; w < (tid >> 6); ++w) woff += wsum[w];
    int run = woff + incl - s;
    #pragma unroll
    for (int u = 0; u < BPT; ++u) {
        bbase[b0 + u] = run;
        prevk[b0 + u] = prv[u];
        run += tot[u];
    }
    __syncthreads();

    // scatter this block's element range (same ranges as hist_k!)
    const int per  = n / HB;
    const int base = k * per;
    for (int i = tid; i < per; i += T) {
        const float t = target[base + i];
        const float p = pred[base + i];
        const int b = bin_of(t);
        const int r = atomicAdd(&lcnt[b], 1);      // LDS atomic only
        const int pos = bbase[b] + prevk[b] + r;
        ts[pos] = t;
        ps[pos] = p;
    }

    if (k == 0) {
        for (int b = tid; b < NBINS; b += T) Bg[b] = bbase[b];
        if (tid == 0) Bg[NBINS] = n;
    }
}

// K3: sorted-prefix hinge sums. Plain partials store, no fences.
__global__ __launch_bounds__(T) void rank_k(const float* __restrict__ ts,
                                            const float* __restrict__ ps,
                                            const int* __restrict__ B,
                                            float* __restrict__ partials, int n) {
    const int nblk = (int)gridDim.x;
    const int g = nblk - 1 - (int)blockIdx.x;   // heavy-first
    const int q = g * RT;

    float ti[RT], ci[RT];
    #pragma unroll
    for (int r = 0; r < RT; ++r) {
        ti[r] = ts[q + r];
        ci[r] = MARGIN - ps[q + r];
    }

    const int Blo = B[bin_of(ti[0])];            // j < Blo: qualifies for all rows
    const int Bhi = B[bin_of(ti[RT - 1]) + 1];   // j >= Bhi: qualifies for none
    const int M0 = Blo & ~3;
    int M1 = (Bhi + 3) & ~3;
    if (M1 > n) M1 = n;

    float sum[RT];
    #pragma unroll
    for (int r = 0; r < RT; ++r) sum[r] = 0.f;

    const float4* __restrict__ p4 = (const float4*)ps;
    const float4* __restrict__ t4 = (const float4*)ts;

    // Full region: unconditional hinge, 3 VALU/pair.
    const int f4 = M0 >> 2;
    for (int j = (int)threadIdx.x; j < f4; j += T) {
        const float4 pj = p4[j];
        #pragma unroll
        for (int r = 0; r < RT; ++r) {
            sum[r] += fmaxf(0.f, ci[r] + pj.x);
            sum[r] += fmaxf(0.f, ci[r] + pj.y);
            sum[r] += fmaxf(0.f, ci[r] + pj.z);
            sum[r] += fmaxf(0.f, ci[r] + pj.w);
        }
    }

    // Boundary band: exact strict compares + ballot counts.
    unsigned int cnt[RT];
    #pragma unroll
    for (int r = 0; r < RT; ++r) cnt[r] = 0u;

    const int m4lo = M0 >> 2, m4hi = M1 >> 2;
    const int iters = (m4hi - m4lo + T - 1) / T;   // block-uniform
    for (int it = 0; it < iters; ++it) {
        const int j = m4lo + it * T + (int)threadIdx.x;
        const bool inb = j < m4hi;
        const int jc = inb ? j : m4lo;
        const float4 tj = t4[jc];
        const float4 pj = p4[jc];
        #pragma unroll
        for (int r = 0; r < RT; ++r) {
            { bool m = inb && (tj.x < ti[r]); float h = fmaxf(0.f, ci[r] + pj.x);
              sum[r] += m ? h : 0.f; cnt[r] += (unsigned)__popcll(__ballot(m)); }
            { bool m = inb && (tj.y < ti[r]); float h = fmaxf(0.f, ci[r] + pj.y);
              sum[r] += m ? h : 0.f; cnt[r] += (unsigned)__popcll(__ballot(m)); }
            { bool m = inb && (tj.z < ti[r]); float h = fmaxf(0.f, ci[r] + pj.z);
              sum[r] += m ? h : 0.f; cnt[r] += (unsigned)__popcll(__ballot(m)); }
            { bool m = inb && (tj.w < ti[r]); float h = fmaxf(0.f, ci[r] + pj.w);
              sum[r] += m ? h : 0.f; cnt[r] += (unsigned)__popcll(__ballot(m)); }
        }
    }

    // Block-level reduction.
    __shared__ float ls[T / 64][RT];
    __shared__ unsigned int lc[T / 64][RT];
    const int lane = (int)threadIdx.x & 63;
    const int wv   = (int)threadIdx.x >> 6;
    #pragma unroll
    for (int r = 0; r < RT; ++r) {
        float sv = sum[r];
        #pragma unroll
        for (int off = 32; off > 0; off >>= 1) sv += __shfl_down(sv, off, 64);
        if (lane == 0) { ls[wv][r] = sv; lc[wv][r] = cnt[r]; }
    }
    __syncthreads();

    float val = 0.f;
    if ((int)threadIdx.x < RT) {
        float sv = 0.f;
        unsigned int c = (unsigned int)M0;       // full region counts for every row
        #pragma unroll
        for (int w = 0; w < T / 64; ++w) { sv += ls[w][threadIdx.x]; c += lc[w][threadIdx.x]; }
        val = (c > 0u) ? sv / (float)c : 0.f;
    }
    if ((int)threadIdx.x < 64) {
        #pragma unroll
        for (int off = 8; off > 0; off >>= 1) val += __shfl_down(val, off, 64);
    }
    if (threadIdx.x == 0) partials[blockIdx.x] = val;
}

// K4: deterministic fixed-order reduction of partials.
__global__ __launch_bounds__(T) void final_k(const float* __restrict__ partials,
                                             float* __restrict__ out, int n, int nblk) {
    double s = 0.0;
    for (int i = (int)threadIdx.x; i < nblk; i += T) s += (double)partials[i];
    #pragma unroll
    for (int off = 32; off > 0; off >>= 1) s += __shfl_down(s, off, 64);
    __shared__ double sd[T / 64];
    const int lane = (int)threadIdx.x & 63, wv = (int)threadIdx.x >> 6;
    if (lane == 0) sd[wv] = s;
    __syncthreads();
    if (threadIdx.x == 0) {
        double t = 0.0;
        #pragma unroll
        for (int w = 0; w < T / 64; ++w) t += sd[w];
        out[0] = (float)(t / (double)n);
    }
}

extern "C" void kernel_launch(void* const* d_in, const int* in_sizes, int n_in,
                              void* d_out, int out_size, void* d_ws, size_t ws_size,
                              hipStream_t stream) {
    const float* pred   = (const float*)d_in[0];
    const float* target = (const float*)d_in[1];
    const int n = in_sizes[0];                 // 16384
    const int nblk = n / RT;                   // 1024

    char* w = (char*)d_ws;
    size_t o = 0;
    auto alloc = [&](size_t bytes) {
        void* p = w + o;
        o = (o + bytes + 255) & ~(size_t)255;
        return p;
    };
    float* ts       = (float*)alloc((size_t)n * 4);
    float* ps       = (float*)alloc((size_t)n * 4);
    int*   H        = (int*)alloc((size_t)NBINS * HB * 4);
    int*   B        = (int*)alloc((size_t)(NBINS + 1) * 4);
    float* partials = (float*)alloc((size_t)nblk * 4);

    hist_k<<<HB, T, 0, stream>>>(target, H, n);
    scatter_k<<<HB, T, 0, stream>>>(pred, target, H, ts, ps, B, n);
    rank_k<<<nblk, T, 0, stream>>>(ts, ps, B, partials, n);
    final_k<<<1, T, 0, stream>>>(partials, (float*)d_out, n, nblk);
}

// Round 5
// 85.263 us; speedup vs baseline: 2.1304x; 1.0707x over previous
//
#include <hip/hip_runtime.h>

// RankingLoss via bucket-ordering. 4 stream-ordered dispatches, NO device fences,
// no contended global atomics (R2 lesson). R5 fixes R4's OOB: HB=16 so each
// block's element range (1024) == T float4s exactly (R4 had 64 blocks x 256 elems
// but 256 threads reading a float4 each -> 4x overrun, OOB scatter, core dump).
//   K1 hist_k   (16 blocks): per-block private histograms (LDS), H[blk][bin].
//   K2 scatter_k(16 blocks): redundant in-LDS scan of H -> exact sorted position
//                            = binbase + prev-blocks-count + LDS local rank.
//   K3 rank_k (1024 blocks): sorted-prefix hinge sums. Full region: 3 VALU/pair.
//                            Boundary band: exact compare + ballot.
//   K4 final_k  (1 block):   deterministic fixed-order double sum of partials.

constexpr float MARGIN = 0.1f;
constexpr int NBINS = 256;    // == T: one bin per thread in the scan
constexpr int HB    = 16;     // hist/scatter blocks; per-block range = n/HB = 1024
constexpr int RT    = 16;     // rows per rank block
constexpr int T     = 256;    // threads per block

__device__ __forceinline__ int bin_of(float t) {
    int b = (int)(t * (float)NBINS);   // monotone; equal t -> equal bin
    b = b < 0 ? 0 : (b > NBINS - 1 ? NBINS - 1 : b);
    return b;
}

// K1: per-block private histograms, H[blk*NBINS + bin]. No global zeroing needed.
__global__ __launch_bounds__(T) void hist_k(const float* __restrict__ target,
                                            int* __restrict__ H, int n) {
    __shared__ int lh[NBINS];
    const int tid = (int)threadIdx.x;
    lh[tid] = 0;                                   // NBINS == T
    __syncthreads();
    const int per = n / HB;                        // 1024 elems == 256 float4s
    const float4 tv = ((const float4*)(target + (int)blockIdx.x * per))[tid];
    atomicAdd(&lh[bin_of(tv.x)], 1);
    atomicAdd(&lh[bin_of(tv.y)], 1);
    atomicAdd(&lh[bin_of(tv.z)], 1);
    atomicAdd(&lh[bin_of(tv.w)], 1);
    __syncthreads();
    H[(int)blockIdx.x * NBINS + tid] = lh[tid];    // coalesced
}

// K2: redundant in-block scan of H + exact scatter (LDS atomics only).
__global__ __launch_bounds__(T) void scatter_k(const float* __restrict__ pred,
                                               const float* __restrict__ target,
                                               const int* __restrict__ H,
                                               float* __restrict__ ts,
                                               float* __restrict__ ps,
                                               int* __restrict__ Bg, int n) {
    __shared__ int bbase[NBINS];   // exclusive bin prefix (global start of bin)
    __shared__ int prevk[NBINS];   // count of this bin in element-blocks < k
    __shared__ int lcnt[NBINS];    // local (within-block) rank counters
    __shared__ int wsum[T / 64];

    const int tid = (int)threadIdx.x;
    const int k   = (int)blockIdx.x;

    // one bin per thread; H[q][bin=tid] is lane-coalesced for each q
    int tot = 0, prv = 0;
    #pragma unroll
    for (int q = 0; q < HB; ++q) {
        const int h = H[q * NBINS + tid];
        tot += h;
        prv += (q < k) ? h : 0;
    }
    lcnt[tid] = 0;

    // exclusive prefix across the block (1 value/thread)
    int incl = tot;
    #pragma unroll
    for (int off = 1; off < 64; off <<= 1) {
        int v = __shfl_up(incl, off, 64);
        if ((tid & 63) >= off) incl += v;
    }
    if ((tid & 63) == 63) wsum[tid >> 6] = incl;
    __syncthreads();
    int woff = 0;
    for (int w = 0; w < (tid >> 6); ++w) woff += wsum[w];
    bbase[tid] = woff + incl - tot;
    prevk[tid] = prv;
    __syncthreads();

    // scatter this block's element range (same ranges as hist_k!)
    const int per = n / HB;                        // 1024 -> 1 float4/thread
    const float4 tv = ((const float4*)(target + k * per))[tid];
    const float4 pv = ((const float4*)(pred   + k * per))[tid];
    {
        const int b = bin_of(tv.x); const int r = atomicAdd(&lcnt[b], 1);
        const int pos = bbase[b] + prevk[b] + r; ts[pos] = tv.x; ps[pos] = pv.x;
    }
    {
        const int b = bin_of(tv.y); const int r = atomicAdd(&lcnt[b], 1);
        const int pos = bbase[b] + prevk[b] + r; ts[pos] = tv.y; ps[pos] = pv.y;
    }
    {
        const int b = bin_of(tv.z); const int r = atomicAdd(&lcnt[b], 1);
        const int pos = bbase[b] + prevk[b] + r; ts[pos] = tv.z; ps[pos] = pv.z;
    }
    {
        const int b = bin_of(tv.w); const int r = atomicAdd(&lcnt[b], 1);
        const int pos = bbase[b] + prevk[b] + r; ts[pos] = tv.w; ps[pos] = pv.w;
    }

    if (k == 0) {
        Bg[tid] = bbase[tid];
        if (tid == 0) Bg[NBINS] = n;
    }
}

// K3: sorted-prefix hinge sums. Plain partials store, no fences.
__global__ __launch_bounds__(T) void rank_k(const float* __restrict__ ts,
                                            const float* __restrict__ ps,
                                            const int* __restrict__ B,
                                            float* __restrict__ partials, int n) {
    const int nblk = (int)gridDim.x;
    const int g = nblk - 1 - (int)blockIdx.x;   // heavy-first
    const int q = g * RT;

    float ti[RT], ci[RT];
    #pragma unroll
    for (int r = 0; r < RT; ++r) {
        ti[r] = ts[q + r];
        ci[r] = MARGIN - ps[q + r];
    }

    const int Blo = B[bin_of(ti[0])];            // j < Blo: qualifies for all rows
    const int Bhi = B[bin_of(ti[RT - 1]) + 1];   // j >= Bhi: qualifies for none
    const int M0 = Blo & ~3;
    int M1 = (Bhi + 3) & ~3;
    if (M1 > n) M1 = n;

    float sum[RT];
    #pragma unroll
    for (int r = 0; r < RT; ++r) sum[r] = 0.f;

    const float4* __restrict__ p4 = (const float4*)ps;
    const float4* __restrict__ t4 = (const float4*)ts;

    // Full region: unconditional hinge, 3 VALU/pair.
    const int f4 = M0 >> 2;
    for (int j = (int)threadIdx.x; j < f4; j += T) {
        const float4 pj = p4[j];
        #pragma unroll
        for (int r = 0; r < RT; ++r) {
            sum[r] += fmaxf(0.f, ci[r] + pj.x);
            sum[r] += fmaxf(0.f, ci[r] + pj.y);
            sum[r] += fmaxf(0.f, ci[r] + pj.z);
            sum[r] += fmaxf(0.f, ci[r] + pj.w);
        }
    }

    // Boundary band: exact strict compares + ballot counts.
    unsigned int cnt[RT];
    #pragma unroll
    for (int r = 0; r < RT; ++r) cnt[r] = 0u;

    const int m4lo = M0 >> 2, m4hi = M1 >> 2;
    const int iters = (m4hi - m4lo + T - 1) / T;   // block-uniform
    for (int it = 0; it < iters; ++it) {
        const int j = m4lo + it * T + (int)threadIdx.x;
        const bool inb = j < m4hi;
        const int jc = inb ? j : m4lo;
        const float4 tj = t4[jc];
        const float4 pj = p4[jc];
        #pragma unroll
        for (int r = 0; r < RT; ++r) {
            { bool m = inb && (tj.x < ti[r]); float h = fmaxf(0.f, ci[r] + pj.x);
              sum[r] += m ? h : 0.f; cnt[r] += (unsigned)__popcll(__ballot(m)); }
            { bool m = inb && (tj.y < ti[r]); float h = fmaxf(0.f, ci[r] + pj.y);
              sum[r] += m ? h : 0.f; cnt[r] += (unsigned)__popcll(__ballot(m)); }
            { bool m = inb && (tj.z < ti[r]); float h = fmaxf(0.f, ci[r] + pj.z);
              sum[r] += m ? h : 0.f; cnt[r] += (unsigned)__popcll(__ballot(m)); }
            { bool m = inb && (tj.w < ti[r]); float h = fmaxf(0.f, ci[r] + pj.w);
              sum[r] += m ? h : 0.f; cnt[r] += (unsigned)__popcll(__ballot(m)); }
        }
    }

    // Block-level reduction.
    __shared__ float ls[T / 64][RT];
    __shared__ unsigned int lc[T / 64][RT];
    const int lane = (int)threadIdx.x & 63;
    const int wv   = (int)threadIdx.x >> 6;
    #pragma unroll
    for (int r = 0; r < RT; ++r) {
        float sv = sum[r];
        #pragma unroll
        for (int off = 32; off > 0; off >>= 1) sv += __shfl_down(sv, off, 64);
        if (lane == 0) { ls[wv][r] = sv; lc[wv][r] = cnt[r]; }
    }
    __syncthreads();

    float val = 0.f;
    if ((int)threadIdx.x < RT) {
        float sv = 0.f;
        unsigned int c = (unsigned int)M0;       // full region counts for every row
        #pragma unroll
        for (int w = 0; w < T / 64; ++w) { sv += ls[w][threadIdx.x]; c += lc[w][threadIdx.x]; }
        val = (c > 0u) ? sv / (float)c : 0.f;
    }
    if ((int)threadIdx.x < 64) {
        #pragma unroll
        for (int off = 8; off > 0; off >>= 1) val += __shfl_down(val, off, 64);
    }
    if (threadIdx.x == 0) partials[blockIdx.x] = val;
}

// K4: deterministic fixed-order reduction of partials (1024 floats, 1 float4/thread).
__global__ __launch_bounds__(T) void final_k(const float* __restrict__ partials,
                                             float* __restrict__ out, int n, int nblk) {
    const int n4 = nblk >> 2;
    double s = 0.0;
    for (int i = (int)threadIdx.x; i < n4; i += T) {
        float4 v = ((const float4*)partials)[i];
        s += (double)v.x + (double)v.y + (double)v.z + (double)v.w;
    }
    #pragma unroll
    for (int off = 32; off > 0; off >>= 1) s += __shfl_down(s, off, 64);
    __shared__ double sd[T / 64];
    const int lane = (int)threadIdx.x & 63, wv = (int)threadIdx.x >> 6;
    if (lane == 0) sd[wv] = s;
    __syncthreads();
    if (threadIdx.x == 0) {
        double t = 0.0;
        #pragma unroll
        for (int w = 0; w < T / 64; ++w) t += sd[w];
        out[0] = (float)(t / (double)n);
    }
}

extern "C" void kernel_launch(void* const* d_in, const int* in_sizes, int n_in,
                              void* d_out, int out_size, void* d_ws, size_t ws_size,
                              hipStream_t stream) {
    const float* pred   = (const float*)d_in[0];
    const float* target = (const float*)d_in[1];
    const int n = in_sizes[0];                 // 16384
    const int nblk = n / RT;                   // 1024

    char* w = (char*)d_ws;
    size_t o = 0;
    auto alloc = [&](size_t bytes) {
        void* p = w + o;
        o = (o + bytes + 255) & ~(size_t)255;
        return p;
    };
    float* ts       = (float*)alloc((size_t)n * 4);
    float* ps       = (float*)alloc((size_t)n * 4);
    int*   H        = (int*)alloc((size_t)NBINS * HB * 4);
    int*   B        = (int*)alloc((size_t)(NBINS + 1) * 4);
    float* partials = (float*)alloc((size_t)nblk * 4);

    hist_k<<<HB, T, 0, stream>>>(target, H, n);
    scatter_k<<<HB, T, 0, stream>>>(pred, target, H, ts, ps, B, n);
    rank_k<<<nblk, T, 0, stream>>>(ts, ps, B, partials, n);
    final_k<<<1, T, 0, stream>>>(partials, (float*)d_out, n, nblk);
}